// Round 12
// baseline (34.472 us; speedup 1.0000x reference)
//
#include <hip/hip_runtime.h>

// Problem constants
#define HDIM 2048
#define NUM_V 32
#define NUM_K 16
#define DK 128
#define DV 128
#define KEY_DIM 2048          // NUM_K*DK
#define VALUE_DIM 4096        // NUM_V*DV
#define CONV_DIM 8192         // 2*KEY_DIM+VALUE_DIM
#define TOTAL_ROWS 12352      // 8192 + 4096 + 32 + 32

// ws layout (floats):
//  [0,      8192)  conv_out   (q | k | v)
//  [8192,  12288)  z
//  [12288, 12320)  b
//  [12320, 12352)  a
//  [12352, 16448)  out_vec (4096)

// d_out layout (floats): [0,2048) hidden_out | [2048,34816) new_conv_state (8192x4)
//                        | [34816, 559104) rec (32x128x128)

typedef __attribute__((ext_vector_type(4))) float f32x4;

// ---------------- Kernel 1: fused GEMV (W_qkv | W_z | W_b | W_a) @ h ----------
// TWO rows per wave, PLAIN loads (no nt — L3 residency matters), 256-thr blocks.
// Halves h-load issue traffic vs 1-row/wave; 6176 waves (~24/CU) remain ample TLP.
__global__ __launch_bounds__(256) void k1_gemv(
    const float* __restrict__ h,          // 2048
    const float* __restrict__ Wqkv,       // 8192 x 2048
    const float* __restrict__ Wz,         // 4096 x 2048
    const float* __restrict__ Wb,         // 32 x 2048
    const float* __restrict__ Wa,         // 32 x 2048
    const float* __restrict__ conv_state, // 8192 x 4
    const float* __restrict__ conv_w,     // 8192 x 4
    float* __restrict__ ws,
    float* __restrict__ out_conv)         // d_out + 2048 : 8192 x 4
{
    const int pair = (blockIdx.x * 256 + threadIdx.x) >> 6;   // 0..6175
    const int lane = threadIdx.x & 63;
    if (pair >= TOTAL_ROWS / 2) return;
    const int row0 = pair * 2;            // region boundaries even -> pair uniform

    const float* w0;
    if (row0 < 8192)       w0 = Wqkv + (size_t)row0 * HDIM;
    else if (row0 < 12288) w0 = Wz   + (size_t)(row0 - 8192) * HDIM;
    else if (row0 < 12320) w0 = Wb   + (size_t)(row0 - 12288) * HDIM;
    else                   w0 = Wa   + (size_t)(row0 - 12320) * HDIM;
    const float* w1 = w0 + HDIM;

    float acc0 = 0.f, acc1 = 0.f;
#pragma unroll
    for (int i = 0; i < 8; ++i) {
        const int idx = (i * 64 + lane) * 4;
        f32x4 h4 = *reinterpret_cast<const f32x4*>(h + idx);
        f32x4 a4 = *reinterpret_cast<const f32x4*>(w0 + idx);
        f32x4 b4 = *reinterpret_cast<const f32x4*>(w1 + idx);
        acc0 += a4.x * h4.x + a4.y * h4.y + a4.z * h4.z + a4.w * h4.w;
        acc1 += b4.x * h4.x + b4.y * h4.y + b4.z * h4.z + b4.w * h4.w;
    }
#pragma unroll
    for (int off = 32; off > 0; off >>= 1) {
        acc0 += __shfl_down(acc0, off, 64);
        acc1 += __shfl_down(acc1, off, 64);
    }

    if (lane == 0) {
        if (row0 < 8192) {
            f32x4 cs0 = *reinterpret_cast<const f32x4*>(conv_state + row0 * 4);
            f32x4 cw0 = *reinterpret_cast<const f32x4*>(conv_w + row0 * 4);
            f32x4 cs1 = *reinterpret_cast<const f32x4*>(conv_state + row0 * 4 + 4);
            f32x4 cw1 = *reinterpret_cast<const f32x4*>(conv_w + row0 * 4 + 4);
            float pre0 = cs0.y * cw0.x + cs0.z * cw0.y + cs0.w * cw0.z + acc0 * cw0.w;
            float pre1 = cs1.y * cw1.x + cs1.z * cw1.y + cs1.w * cw1.z + acc1 * cw1.w;
            ws[row0]     = pre0 / (1.f + expf(-pre0));   // silu -> conv_out
            ws[row0 + 1] = pre1 / (1.f + expf(-pre1));
            f32x4 n0; n0.x = cs0.y; n0.y = cs0.z; n0.z = cs0.w; n0.w = acc0;
            f32x4 n1; n1.x = cs1.y; n1.y = cs1.z; n1.z = cs1.w; n1.w = acc1;
            *reinterpret_cast<f32x4*>(out_conv + row0 * 4)     = n0;
            *reinterpret_cast<f32x4*>(out_conv + row0 * 4 + 4) = n1;
        } else {
            ws[row0]     = acc0;   // z | b | a
            ws[row0 + 1] = acc1;
        }
    }
}

// ---------------- Kernel 2: per-head recurrent state update --------------------
// (R8-proven: 1024 threads, registers hold rec rows between pass 1 and pass 2)
__global__ __launch_bounds__(1024) void k2_rec(
    const float* __restrict__ ws,        // conv_out | z | b | a
    const float* __restrict__ rec_in,    // 32 x 128 x 128
    const float* __restrict__ dt_bias,   // 32
    const float* __restrict__ A_log,     // 32
    const float* __restrict__ norm_w,    // 128
    float* __restrict__ rec_out,         // d_out + 34816
    float* __restrict__ out_vec)         // ws + 12352 (4096 f32)
{
    __shared__ float s_k[128];
    __shared__ float s_q[128];
    __shared__ float s_delta[128];
    __shared__ float s_part[8][128];
    __shared__ float s_red[4];

    const int hh  = blockIdx.x;      // head 0..31
    const int t   = threadIdx.x;     // 0..1023
    const int d   = t & 127;         // column
    const int kkb = t >> 7;          // 0..7 : owns kk in [kkb*16, kkb*16+16)
    const int kh  = hh >> 1;         // key head (VPK = 2)

    const float bv    = ws[12288 + hh];
    const float av    = ws[12320 + hh];
    const float beta  = 1.f / (1.f + expf(-bv));
    const float x     = av + dt_bias[hh];
    const float sp    = fmaxf(x, 0.f) + log1pf(expf(-fabsf(x)));   // softplus
    const float decay = expf(-expf(A_log[hh]) * sp);

    float qr = 0.f, kr = 0.f;
    if (t < 128) {
        qr = ws[kh * 128 + d];
        kr = ws[KEY_DIM + kh * 128 + d];
        float sq = qr * qr, sk = kr * kr;
#pragma unroll
        for (int off = 32; off > 0; off >>= 1) {
            sq += __shfl_down(sq, off, 64);
            sk += __shfl_down(sk, off, 64);
        }
        if ((t & 63) == 0) { s_red[t >> 6] = sq; s_red[2 + (t >> 6)] = sk; }
    }
    __syncthreads();
    if (t < 128) {
        const float ssq = s_red[0] + s_red[1];
        const float ssk = s_red[2] + s_red[3];
        s_q[d] = qr * rsqrtf(ssq + 1e-6f) * 0.08838834764831845f;  // l2norm * 1/sqrt(DK)
        s_k[d] = kr * rsqrtf(ssk + 1e-6f);
    }
    __syncthreads();

    const float* rrow = rec_in  + (size_t)hh * (DK * DV) + kkb * 16 * DV;
    float*       wrow = rec_out + (size_t)hh * (DK * DV) + kkb * 16 * DV;

    float rv[16];
#pragma unroll
    for (int i = 0; i < 16; ++i)
        rv[i] = rrow[i * DV + d];

    float kvp = 0.f;
#pragma unroll
    for (int i = 0; i < 16; ++i)
        kvp += rv[i] * s_k[kkb * 16 + i];
    s_part[kkb][d] = kvp;
    __syncthreads();

    if (t < 128) {
        float kv = 0.f;
#pragma unroll
        for (int j = 0; j < 8; ++j) kv += s_part[j][d];
        kv *= decay;
        const float vv = ws[2 * KEY_DIM + hh * 128 + d];
        s_delta[d] = (vv - kv) * beta;
    }
    __syncthreads();

    const float dlt = s_delta[d];
    float corep = 0.f;
#pragma unroll
    for (int i = 0; i < 16; ++i) {
        const float r = rv[i] * decay + s_k[kkb * 16 + i] * dlt;
        wrow[i * DV + d] = r;
        corep += r * s_q[kkb * 16 + i];
    }
    s_part[kkb][d] = corep;
    __syncthreads();

    float core = 0.f;
    if (t < 128) {
#pragma unroll
        for (int j = 0; j < 8; ++j) core += s_part[j][d];
        float sc = core * core;
#pragma unroll
        for (int off = 32; off > 0; off >>= 1)
            sc += __shfl_down(sc, off, 64);
        if ((t & 63) == 0) s_red[t >> 6] = sc;
    }
    __syncthreads();
    if (t < 128) {
        const float ssc = s_red[0] + s_red[1];
        const float xn  = core * rsqrtf(ssc * (1.f / 128.f) + 1e-6f) * norm_w[d];
        const float zv  = ws[8192 + hh * 128 + d];
        out_vec[hh * 128 + d] = xn * (zv / (1.f + expf(-zv)));   // xn * silu(z)
    }
}

// ---------------- Kernel 3: hidden_out = W_out @ out_vec ----------------------
// one wave per row (R8-proven geometry, untouched).
__global__ __launch_bounds__(256) void k3_out(
    const float* __restrict__ Wout,       // 2048 x 4096
    const float* __restrict__ out_vec,    // 4096 f32
    float* __restrict__ hidden_out)       // d_out[0:2048]
{
    const int row  = (blockIdx.x * 256 + threadIdx.x) >> 6;
    const int lane = threadIdx.x & 63;
    if (row >= HDIM) return;

    const float* wrow = Wout + (size_t)row * VALUE_DIM;
    float acc = 0.f;
#pragma unroll
    for (int i = 0; i < 16; ++i) {
        const int idx = (i * 64 + lane) * 4;
        f32x4 w4 = *reinterpret_cast<const f32x4*>(wrow + idx);
        f32x4 o4 = *reinterpret_cast<const f32x4*>(out_vec + idx);
        acc += w4.x * o4.x + w4.y * o4.y + w4.z * o4.z + w4.w * o4.w;
    }
#pragma unroll
    for (int off = 32; off > 0; off >>= 1)
        acc += __shfl_down(acc, off, 64);
    if (lane == 0) hidden_out[row] = acc;
}

extern "C" void kernel_launch(void* const* d_in, const int* in_sizes, int n_in,
                              void* d_out, int out_size, void* d_ws, size_t ws_size,
                              hipStream_t stream) {
    const float* hidden_in  = (const float*)d_in[0];
    const float* conv_state = (const float*)d_in[1];
    const float* rec_state  = (const float*)d_in[2];
    const float* W_qkv      = (const float*)d_in[3];
    const float* W_z        = (const float*)d_in[4];
    const float* W_b        = (const float*)d_in[5];
    const float* W_a        = (const float*)d_in[6];
    const float* W_out      = (const float*)d_in[7];
    const float* conv_w     = (const float*)d_in[8];
    const float* dt_bias    = (const float*)d_in[9];
    const float* A_log      = (const float*)d_in[10];
    const float* norm_w     = (const float*)d_in[11];

    float* out = (float*)d_out;
    float* ws  = (float*)d_ws;

    // out layout (f32): [0,2048) hidden_out | [2048,34816) new_conv_state | [34816,...) rec
    // k1: 6176 row-pairs, 4 pairs per 256-thread block -> 1544 blocks
    k1_gemv<<<(TOTAL_ROWS / 2) / 4, 256, 0, stream>>>(hidden_in, W_qkv, W_z, W_b, W_a,
                                                      conv_state, conv_w, ws, out + 2048);
    k2_rec<<<NUM_V, 1024, 0, stream>>>(ws, rec_state, dt_bias, A_log, norm_w,
                                       out + 2048 + CONV_DIM * 4, ws + 12352);
    k3_out<<<HDIM / 4, 256, 0, stream>>>(W_out, ws + 12352, out);
}

// Round 13
// 32.099 us; speedup vs baseline: 1.0739x; 1.0739x over previous
//
#include <hip/hip_runtime.h>

// Problem constants
#define HDIM 2048
#define NUM_V 32
#define NUM_K 16
#define DK 128
#define DV 128
#define KEY_DIM 2048          // NUM_K*DK
#define VALUE_DIM 4096        // NUM_V*DV
#define CONV_DIM 8192         // 2*KEY_DIM+VALUE_DIM
#define TOTAL_ROWS 12352      // 8192 + 4096 + 32 + 32

// ws layout (floats):
//  [0,      8192)  conv_out   (q | k | v)
//  [8192,  12288)  z
//  [12288, 12320)  b
//  [12320, 12352)  a
//  [12352, 16448)  out_vec (4096)

// d_out layout (floats): [0,2048) hidden_out | [2048,34816) new_conv_state (8192x4)
//                        | [34816, 559104) rec (32x128x128)

typedef __attribute__((ext_vector_type(4))) float f32x4;

// ---------------- Kernel 1: fused GEMV (W_qkv | W_z | W_b | W_a) @ h ----------
// one wave per row — A/B-proven optimum (beats pair-rows, persistent, LDS-h).
__global__ __launch_bounds__(256) void k1_gemv(
    const float* __restrict__ h,          // 2048
    const float* __restrict__ Wqkv,       // 8192 x 2048
    const float* __restrict__ Wz,         // 4096 x 2048
    const float* __restrict__ Wb,         // 32 x 2048
    const float* __restrict__ Wa,         // 32 x 2048
    const float* __restrict__ conv_state, // 8192 x 4
    const float* __restrict__ conv_w,     // 8192 x 4
    float* __restrict__ ws,
    float* __restrict__ out_conv)         // d_out + 2048 : 8192 x 4
{
    const int row  = (blockIdx.x * 256 + threadIdx.x) >> 6;
    const int lane = threadIdx.x & 63;
    if (row >= TOTAL_ROWS) return;

    const float* wrow;
    if (row < 8192)       wrow = Wqkv + (size_t)row * HDIM;
    else if (row < 12288) wrow = Wz   + (size_t)(row - 8192) * HDIM;
    else if (row < 12320) wrow = Wb   + (size_t)(row - 12288) * HDIM;
    else                  wrow = Wa   + (size_t)(row - 12320) * HDIM;

    float acc = 0.f;
#pragma unroll
    for (int i = 0; i < 8; ++i) {
        const int idx = (i * 64 + lane) * 4;
        f32x4 w4 = *reinterpret_cast<const f32x4*>(wrow + idx);
        f32x4 h4 = *reinterpret_cast<const f32x4*>(h + idx);
        acc += w4.x * h4.x + w4.y * h4.y + w4.z * h4.z + w4.w * h4.w;
    }
#pragma unroll
    for (int off = 32; off > 0; off >>= 1)
        acc += __shfl_down(acc, off, 64);

    if (lane == 0) {
        if (row < 8192) {
            f32x4 cs = *reinterpret_cast<const f32x4*>(conv_state + row * 4);
            f32x4 cw = *reinterpret_cast<const f32x4*>(conv_w + row * 4);
            float pre = cs.y * cw.x + cs.z * cw.y + cs.w * cw.z + acc * cw.w;
            ws[row] = pre / (1.f + expf(-pre));     // silu -> conv_out
            f32x4 n; n.x = cs.y; n.y = cs.z; n.z = cs.w; n.w = acc;
            *reinterpret_cast<f32x4*>(out_conv + row * 4) = n;
        } else {
            ws[row] = acc;   // z / b / a land contiguously by construction
        }
    }
}

// ---------------- Kernel 2: per-head recurrent state update --------------------
// 1024 threads/block (16 waves): thread = (kkb 0..7, d 0..127); each thread
// owns 16 kk-rows for its column d, HELD IN REGISTERS between pass 1 and 2.
__global__ __launch_bounds__(1024) void k2_rec(
    const float* __restrict__ ws,        // conv_out | z | b | a
    const float* __restrict__ rec_in,    // 32 x 128 x 128
    const float* __restrict__ dt_bias,   // 32
    const float* __restrict__ A_log,     // 32
    const float* __restrict__ norm_w,    // 128
    float* __restrict__ rec_out,         // d_out + 34816
    float* __restrict__ out_vec)         // ws + 12352 (4096 f32)
{
    __shared__ float s_k[128];
    __shared__ float s_q[128];
    __shared__ float s_delta[128];
    __shared__ float s_part[8][128];
    __shared__ float s_red[4];

    const int hh  = blockIdx.x;      // head 0..31
    const int t   = threadIdx.x;     // 0..1023
    const int d   = t & 127;         // column
    const int kkb = t >> 7;          // 0..7 : owns kk in [kkb*16, kkb*16+16)
    const int kh  = hh >> 1;         // key head (VPK = 2)

    const float bv    = ws[12288 + hh];
    const float av    = ws[12320 + hh];
    const float beta  = 1.f / (1.f + expf(-bv));
    const float x     = av + dt_bias[hh];
    const float sp    = fmaxf(x, 0.f) + log1pf(expf(-fabsf(x)));   // softplus
    const float decay = expf(-expf(A_log[hh]) * sp);

    float qr = 0.f, kr = 0.f;
    if (t < 128) {
        qr = ws[kh * 128 + d];
        kr = ws[KEY_DIM + kh * 128 + d];
        float sq = qr * qr, sk = kr * kr;
#pragma unroll
        for (int off = 32; off > 0; off >>= 1) {
            sq += __shfl_down(sq, off, 64);
            sk += __shfl_down(sk, off, 64);
        }
        if ((t & 63) == 0) { s_red[t >> 6] = sq; s_red[2 + (t >> 6)] = sk; }
    }
    __syncthreads();
    if (t < 128) {
        const float ssq = s_red[0] + s_red[1];
        const float ssk = s_red[2] + s_red[3];
        s_q[d] = qr * rsqrtf(ssq + 1e-6f) * 0.08838834764831845f;  // l2norm * 1/sqrt(DK)
        s_k[d] = kr * rsqrtf(ssk + 1e-6f);
    }
    __syncthreads();

    const float* rrow = rec_in  + (size_t)hh * (DK * DV) + kkb * 16 * DV;
    float*       wrow = rec_out + (size_t)hh * (DK * DV) + kkb * 16 * DV;

    float rv[16];
#pragma unroll
    for (int i = 0; i < 16; ++i)
        rv[i] = rrow[i * DV + d];

    float kvp = 0.f;
#pragma unroll
    for (int i = 0; i < 16; ++i)
        kvp += rv[i] * s_k[kkb * 16 + i];
    s_part[kkb][d] = kvp;
    __syncthreads();

    if (t < 128) {
        float kv = 0.f;
#pragma unroll
        for (int j = 0; j < 8; ++j) kv += s_part[j][d];
        kv *= decay;
        const float vv = ws[2 * KEY_DIM + hh * 128 + d];
        s_delta[d] = (vv - kv) * beta;
    }
    __syncthreads();

    const float dlt = s_delta[d];
    float corep = 0.f;
#pragma unroll
    for (int i = 0; i < 16; ++i) {
        const float r = rv[i] * decay + s_k[kkb * 16 + i] * dlt;
        wrow[i * DV + d] = r;
        corep += r * s_q[kkb * 16 + i];
    }
    s_part[kkb][d] = corep;
    __syncthreads();

    float core = 0.f;
    if (t < 128) {
#pragma unroll
        for (int j = 0; j < 8; ++j) core += s_part[j][d];
        float sc = core * core;
#pragma unroll
        for (int off = 32; off > 0; off >>= 1)
            sc += __shfl_down(sc, off, 64);
        if ((t & 63) == 0) s_red[t >> 6] = sc;
    }
    __syncthreads();
    if (t < 128) {
        const float ssc = s_red[0] + s_red[1];
        const float xn  = core * rsqrtf(ssc * (1.f / 128.f) + 1e-6f) * norm_w[d];
        const float zv  = ws[8192 + hh * 128 + d];
        out_vec[hh * 128 + d] = xn * (zv / (1.f + expf(-zv)));   // xn * silu(z)
    }
}

// ---------------- Kernel 3: hidden_out = W_out @ out_vec ----------------------
// one wave per row — A/B-proven optimum.
__global__ __launch_bounds__(256) void k3_out(
    const float* __restrict__ Wout,       // 2048 x 4096
    const float* __restrict__ out_vec,    // 4096 f32
    float* __restrict__ hidden_out)       // d_out[0:2048]
{
    const int row  = (blockIdx.x * 256 + threadIdx.x) >> 6;
    const int lane = threadIdx.x & 63;
    if (row >= HDIM) return;

    const float* wrow = Wout + (size_t)row * VALUE_DIM;
    float acc = 0.f;
#pragma unroll
    for (int i = 0; i < 16; ++i) {
        const int idx = (i * 64 + lane) * 4;
        f32x4 w4 = *reinterpret_cast<const f32x4*>(wrow + idx);
        f32x4 o4 = *reinterpret_cast<const f32x4*>(out_vec + idx);
        acc += w4.x * o4.x + w4.y * o4.y + w4.z * o4.z + w4.w * o4.w;
    }
#pragma unroll
    for (int off = 32; off > 0; off >>= 1)
        acc += __shfl_down(acc, off, 64);
    if (lane == 0) hidden_out[row] = acc;
}

extern "C" void kernel_launch(void* const* d_in, const int* in_sizes, int n_in,
                              void* d_out, int out_size, void* d_ws, size_t ws_size,
                              hipStream_t stream) {
    const float* hidden_in  = (const float*)d_in[0];
    const float* conv_state = (const float*)d_in[1];
    const float* rec_state  = (const float*)d_in[2];
    const float* W_qkv      = (const float*)d_in[3];
    const float* W_z        = (const float*)d_in[4];
    const float* W_b        = (const float*)d_in[5];
    const float* W_a        = (const float*)d_in[6];
    const float* W_out      = (const float*)d_in[7];
    const float* conv_w     = (const float*)d_in[8];
    const float* dt_bias    = (const float*)d_in[9];
    const float* A_log      = (const float*)d_in[10];
    const float* norm_w     = (const float*)d_in[11];

    float* out = (float*)d_out;
    float* ws  = (float*)d_ws;

    // out layout (f32): [0,2048) hidden_out | [2048,34816) new_conv_state | [34816,...) rec
    k1_gemv<<<TOTAL_ROWS / 4, 256, 0, stream>>>(hidden_in, W_qkv, W_z, W_b, W_a,
                                                conv_state, conv_w, ws, out + 2048);
    k2_rec<<<NUM_V, 1024, 0, stream>>>(ws, rec_state, dt_bias, A_log, norm_w,
                                       out + 2048 + CONV_DIM * 4, ws + 12352);
    k3_out<<<HDIM / 4, 256, 0, stream>>>(W_out, ws + 12352, out);
}